// Round 6
// baseline (1402.361 us; speedup 1.0000x reference)
//
#include <hip/hip_runtime.h>

// ---------------------------------------------------------------------------
// EnterpriseGNN: 3-layer GCN on MI355X.
//   h = relu( dinv[n] * ( sum_{e:dst=n} w_e * g[src_e]  +  g[n] ) + b )
//   g = dinv .* (x@W),  dinv = rsqrt(deg+1),  deg = sum_{e:dst=n} w_e.
//
// R1: flat grid + per-(edge,feat) global atomics: 332 us, 1.95 TB/s moved.
// R2: CSR pull; build's random global atomics wall (~23 G/s).
// R3-R5: bucket-sort + one-persistent-block-per-bucket LDS agg. MLP raised
//     34x across rounds; time stuck 700->562 us at ~300 GB/s fetch. The wall
//     follows the persistent-loop structure, NOT the gather pattern (R1
//     proved 1.95 TB/s on the same gathers).
// R6: flat aggregation. One block per 256-edge chunk (12.5k blocks), 8
//     fully-unrolled gather steps (all loads in flight before LDS atomics),
//     32x33 LDS tile per bucket segment, COALESCED global-atomic flush into
//     acc[] (51 MB; coalesced same-line atomics run ~300 G/s per R1).
//     Epilogues (self-loop/dinv/bias/relu + next GEMM) in streaming kernels.
// ---------------------------------------------------------------------------

#define G 256            // producer blocks for hist/scatter
#define BSH 5            // log2(nodes per bucket)
#define BNODES 32
#define MAXB 3200        // >= ceil(100000/32)=3125
#define CHUNK 256        // edges per agg block

// --- bucket build ----------------------------------------------------------

__global__ __launch_bounds__(256) void hist_kernel(
    const int* __restrict__ dst, int* __restrict__ blockHist, int E, int B) {
    __shared__ int hist[MAXB];
    for (int i = threadIdx.x; i < B; i += 256) hist[i] = 0;
    __syncthreads();
    int per = (E + G - 1) / G;
    int e0 = blockIdx.x * per, e1 = min(e0 + per, E);
    for (int e = e0 + threadIdx.x; e < e1; e += 256)
        atomicAdd(&hist[((unsigned)dst[e]) >> BSH], 1);
    __syncthreads();
    for (int i = threadIdx.x; i < B; i += 256)
        blockHist[(size_t)i * G + blockIdx.x] = hist[i];
}

__global__ __launch_bounds__(256) void scan_cols_kernel(
    int* __restrict__ blockHist, int* __restrict__ bucketTotal) {
    __shared__ int tmp[256];
    int b = blockIdx.x;
    int v = blockHist[(size_t)b * G + threadIdx.x];
    tmp[threadIdx.x] = v;
    __syncthreads();
    for (int off = 1; off < 256; off <<= 1) {
        int t = (threadIdx.x >= off) ? tmp[threadIdx.x - off] : 0;
        __syncthreads();
        tmp[threadIdx.x] += t;
        __syncthreads();
    }
    blockHist[(size_t)b * G + threadIdx.x] = tmp[threadIdx.x] - v;
    if (threadIdx.x == 255) bucketTotal[b] = tmp[255];
}

// exclusive scan of bucket totals (B <= 4096): 1024 threads, 4 per thread
__global__ __launch_bounds__(1024) void base_scan_kernel(
    const int* __restrict__ bucketTotal, int* __restrict__ bucketBase,
    int B, int E) {
    __shared__ int tmp[1024];
    int v[4], s = 0;
#pragma unroll
    for (int k = 0; k < 4; k++) {
        int i = 4 * threadIdx.x + k;
        v[k] = (i < B) ? bucketTotal[i] : 0;
        s += v[k];
    }
    tmp[threadIdx.x] = s;
    __syncthreads();
    for (int off = 1; off < 1024; off <<= 1) {
        int t = (threadIdx.x >= off) ? tmp[threadIdx.x - off] : 0;
        __syncthreads();
        tmp[threadIdx.x] += t;
        __syncthreads();
    }
    int ex = tmp[threadIdx.x] - s;
#pragma unroll
    for (int k = 0; k < 4; k++) {
        int i = 4 * threadIdx.x + k;
        if (i < B) bucketBase[i] = ex;
        ex += v[k];
    }
    if (threadIdx.x == 0) bucketBase[B] = E;
}

// rec.x = src | (dst & 31) << 20 ; rec.y = bits(w). LDS cursors only.
__global__ __launch_bounds__(256) void scatter_kernel(
    const int* __restrict__ src, const int* __restrict__ dst,
    const float* __restrict__ w, const int* __restrict__ blockHist,
    const int* __restrict__ bucketBase, uint2* __restrict__ recs,
    int E, int B) {
    __shared__ int cursor[MAXB];
    for (int i = threadIdx.x; i < B; i += 256)
        cursor[i] = bucketBase[i] + blockHist[(size_t)i * G + blockIdx.x];
    __syncthreads();
    int per = (E + G - 1) / G;
    int e0 = blockIdx.x * per, e1 = min(e0 + per, E);
    for (int e = e0 + threadIdx.x; e < e1; e += 256) {
        int d = dst[e];
        int b = ((unsigned)d) >> BSH;
        int pos = atomicAdd(&cursor[b], 1);
        recs[pos] = make_uint2((unsigned)src[e] |
                               ((unsigned)(d & (BNODES - 1)) << 20),
                               __float_as_uint(w[e]));
    }
}

// deg per bucket from records -> dinv = rsqrt(deg+1)
__global__ __launch_bounds__(256) void degdinv_kernel(
    const int* __restrict__ bucketBase, const uint2* __restrict__ recs,
    float* __restrict__ dinv, int N) {
    __shared__ float deg[BNODES];
    if (threadIdx.x < BNODES) deg[threadIdx.x] = 0.f;
    __syncthreads();
    int b = blockIdx.x;
    int r0 = bucketBase[b], r1 = bucketBase[b + 1];
    for (int i = r0 + threadIdx.x; i < r1; i += 256) {
        uint2 rec = recs[i];
        atomicAdd(&deg[rec.x >> 20], __uint_as_float(rec.y));
    }
    __syncthreads();
    if (threadIdx.x < BNODES) {
        int n = b * BNODES + threadIdx.x;
        if (n < N) dinv[n] = rsqrtf(deg[threadIdx.x] + 1.f);
    }
}

// --- g1 = dinv .* (x @ W1)   (128 -> 32) -----------------------------------

__global__ __launch_bounds__(256) void gemm1_kernel(
    const float* __restrict__ x, const float* __restrict__ W1,
    const float* __restrict__ dinv, float* __restrict__ g1, int N) {
    __shared__ float sW[128 * 32];
    __shared__ float sx[8][128];
    for (int i = threadIdx.x; i < 128 * 32; i += 256) sW[i] = W1[i];
    int node0 = blockIdx.x * 8;
    for (int i = threadIdx.x; i < 8 * 128; i += 256) {
        int r = i >> 7, c = i & 127;
        int n = node0 + r;
        sx[r][c] = (n < N) ? x[(size_t)n * 128 + c] : 0.f;
    }
    __syncthreads();
    int local = threadIdx.x >> 5;
    int j = threadIdx.x & 31;
    int n = node0 + local;
    if (n < N) {
        float acc = 0.f;
#pragma unroll 16
        for (int k = 0; k < 128; k++) acc += sx[local][k] * sW[k * 32 + j];
        g1[(size_t)n * 32 + j] = acc * dinv[n];
    }
}

// --- flat aggregation: one block per 256-edge chunk ------------------------
// F=32: 8 lanes/edge (float4), 32 slots, 8 unrolled steps.

__global__ __launch_bounds__(256) void agg1_flat_kernel(
    const int* __restrict__ bucketBase, const uint2* __restrict__ recs,
    const float* __restrict__ g1, float* __restrict__ acc1, int E, int B) {
    const int FS = 33;
    __shared__ float tile[BNODES * FS];
    int c0 = blockIdx.x * CHUNK;
    int c1 = min(c0 + CHUNK, E);
    // largest b with bucketBase[b] <= c0  (uniform across block)
    int lo = 0, hi = B - 1;
    while (lo < hi) {
        int mid = (lo + hi + 1) >> 1;
        if (bucketBase[mid] <= c0) lo = mid; else hi = mid - 1;
    }
    int b = lo;
    const float4* g4 = (const float4*)g1;
    int slot = threadIdx.x >> 3;       // edge slot 0..31
    int l = threadIdx.x & 7;           // float4 lane in row

    int pos = c0;
    while (pos < c1) {
        int nb = bucketBase[b + 1];
        if (nb <= pos) { b++; continue; }
        int segEnd = min(c1, nb);
        for (int i = threadIdx.x; i < BNODES * FS; i += 256) tile[i] = 0.f;
        __syncthreads();
        // all loads issued before atomics: full unroll, clamped indices
        uint2 r[8];
        float4 v[8];
#pragma unroll
        for (int k = 0; k < 8; k++) {
            int i = pos + slot + 32 * k;
            r[k] = recs[min(i, segEnd - 1)];
        }
#pragma unroll
        for (int k = 0; k < 8; k++)
            v[k] = g4[(size_t)(r[k].x & 0xFFFFFu) * 8 + l];
#pragma unroll
        for (int k = 0; k < 8; k++) {
            int i = pos + slot + 32 * k;
            float w = (i < segEnd) ? __uint_as_float(r[k].y) : 0.f;
            int t = (int)(r[k].x >> 20) * FS + 4 * l;
            atomicAdd(&tile[t + 0], w * v[k].x);
            atomicAdd(&tile[t + 1], w * v[k].y);
            atomicAdd(&tile[t + 2], w * v[k].z);
            atomicAdd(&tile[t + 3], w * v[k].w);
        }
        __syncthreads();
        // coalesced atomic flush of bucket b's 32x32 tile
        int node0 = b * BNODES;
        for (int i = threadIdx.x; i < BNODES * 32; i += 256) {
            int loc = i >> 5, f = i & 31;
            atomicAdd(&acc1[(size_t)(node0 + loc) * 32 + f], tile[loc * FS + f]);
        }
        __syncthreads();
        pos = segEnd;
    }
}

// F=16: 4 lanes/edge (float4), 64 slots, 4 unrolled steps.
__global__ __launch_bounds__(256) void agg2_flat_kernel(
    const int* __restrict__ bucketBase, const uint2* __restrict__ recs,
    const float* __restrict__ g2, float* __restrict__ acc2, int E, int B) {
    const int FS = 17;
    __shared__ float tile[BNODES * FS];
    int c0 = blockIdx.x * CHUNK;
    int c1 = min(c0 + CHUNK, E);
    int lo = 0, hi = B - 1;
    while (lo < hi) {
        int mid = (lo + hi + 1) >> 1;
        if (bucketBase[mid] <= c0) lo = mid; else hi = mid - 1;
    }
    int b = lo;
    const float4* g4 = (const float4*)g2;
    int slot = threadIdx.x >> 2;       // edge slot 0..63
    int l = threadIdx.x & 3;

    int pos = c0;
    while (pos < c1) {
        int nb = bucketBase[b + 1];
        if (nb <= pos) { b++; continue; }
        int segEnd = min(c1, nb);
        for (int i = threadIdx.x; i < BNODES * FS; i += 256) tile[i] = 0.f;
        __syncthreads();
        uint2 r[4];
        float4 v[4];
#pragma unroll
        for (int k = 0; k < 4; k++) {
            int i = pos + slot + 64 * k;
            r[k] = recs[min(i, segEnd - 1)];
        }
#pragma unroll
        for (int k = 0; k < 4; k++)
            v[k] = g4[(size_t)(r[k].x & 0xFFFFFu) * 4 + l];
#pragma unroll
        for (int k = 0; k < 4; k++) {
            int i = pos + slot + 64 * k;
            float w = (i < segEnd) ? __uint_as_float(r[k].y) : 0.f;
            int t = (int)(r[k].x >> 20) * FS + 4 * l;
            atomicAdd(&tile[t + 0], w * v[k].x);
            atomicAdd(&tile[t + 1], w * v[k].y);
            atomicAdd(&tile[t + 2], w * v[k].z);
            atomicAdd(&tile[t + 3], w * v[k].w);
        }
        __syncthreads();
        int node0 = b * BNODES;
        for (int i = threadIdx.x; i < BNODES * 16; i += 256) {
            int loc = i >> 4, f = i & 15;
            atomicAdd(&acc2[(size_t)(node0 + loc) * 16 + f], tile[loc * FS + f]);
        }
        __syncthreads();
        pos = segEnd;
    }
}

// --- combine1: h1 = relu(dinv*(acc1+g1)+b1); g2 = dinv .* (h1@W2) ----------

__global__ __launch_bounds__(256) void combine1_kernel(
    const float* __restrict__ acc1, const float* __restrict__ g1,
    const float* __restrict__ dinv, const float* __restrict__ b1,
    const float* __restrict__ W2, float* __restrict__ g2, int N) {
    __shared__ float sW[32 * 16];
    __shared__ float sh[16][33];
    for (int i = threadIdx.x; i < 32 * 16; i += 256) sW[i] = W2[i];
    int node0 = blockIdx.x * 16;
    for (int i = threadIdx.x; i < 16 * 32; i += 256) {
        int r = i >> 5, c = i & 31;
        int n = node0 + r;
        float v = 0.f;
        if (n < N) {
            size_t o = (size_t)n * 32 + c;
            v = fmaxf(dinv[n] * (acc1[o] + g1[o]) + b1[c], 0.f);
        }
        sh[r][c] = v;
    }
    __syncthreads();
    int local = threadIdx.x >> 4;
    int j = threadIdx.x & 15;
    int n = node0 + local;
    if (n < N) {
        float acc = 0.f;
#pragma unroll
        for (int k = 0; k < 32; k++) acc += sh[local][k] * sW[k * 16 + j];
        g2[(size_t)n * 16 + j] = acc * dinv[n];
    }
}

// --- final: out = relu(dinv*(acc2+g2)+b2) @ Wout + bout --------------------

__global__ __launch_bounds__(256) void final_kernel(
    const float* __restrict__ acc2, const float* __restrict__ g2,
    const float* __restrict__ dinv, const float* __restrict__ b2,
    const float* __restrict__ Wout, const float* __restrict__ bout,
    float* __restrict__ out, int N) {
    int n = blockIdx.x * blockDim.x + threadIdx.x;
    if (n >= N) return;
    float di = dinv[n];
    float o0 = bout[0], o1 = bout[1], o2 = bout[2];
#pragma unroll
    for (int k = 0; k < 16; k++) {
        size_t o = (size_t)n * 16 + k;
        float v = fmaxf(di * (acc2[o] + g2[o]) + b2[k], 0.f);
        o0 += v * Wout[k * 3 + 0];
        o1 += v * Wout[k * 3 + 1];
        o2 += v * Wout[k * 3 + 2];
    }
    out[(size_t)n * 3 + 0] = o0;
    out[(size_t)n * 3 + 1] = o1;
    out[(size_t)n * 3 + 2] = o2;
}

extern "C" void kernel_launch(void* const* d_in, const int* in_sizes, int n_in,
                              void* d_out, int out_size, void* d_ws, size_t ws_size,
                              hipStream_t stream) {
    const float* x    = (const float*)d_in[0];
    const int* ei     = (const int*)d_in[1];   // [2,E]: row0=src, row1=dst
    const float* ew   = (const float*)d_in[2];
    const float* W1   = (const float*)d_in[3];
    const float* b1   = (const float*)d_in[4];
    const float* W2   = (const float*)d_in[5];
    const float* b2   = (const float*)d_in[6];
    const float* Wout = (const float*)d_in[7];
    const float* bout = (const float*)d_in[8];
    float* out = (float*)d_out;

    const int N = in_sizes[0] / 128;
    const int E = in_sizes[2];
    const int* src = ei;
    const int* dst = ei + E;
    const int B = (N + BNODES - 1) >> BSH;      // 3125 for N=100K

    // ws (4B words): recs[2E] | acc1[32N] | acc2[16N] | g1[32N] | g2[16N] |
    //                dinv[N] | blockHist[B*G] | bucketTotal[B] | bucketBase[B+1]
    float* ws = (float*)d_ws;
    uint2* recs = (uint2*)ws;
    float* acc1 = ws + (size_t)2 * E;
    float* acc2 = acc1 + (size_t)32 * N;
    float* g1   = acc2 + (size_t)16 * N;
    float* g2   = g1 + (size_t)32 * N;
    float* dinv = g2 + (size_t)16 * N;
    int* blockHist   = (int*)(dinv + N);
    int* bucketTotal = blockHist + (size_t)B * G;
    int* bucketBase  = bucketTotal + B;

    // zero accumulators (contiguous 48N floats)
    hipMemsetAsync(acc1, 0, (size_t)48 * N * sizeof(float), stream);

    hist_kernel<<<G, 256, 0, stream>>>(dst, blockHist, E, B);
    scan_cols_kernel<<<B, 256, 0, stream>>>(blockHist, bucketTotal);
    base_scan_kernel<<<1, 1024, 0, stream>>>(bucketTotal, bucketBase, B, E);
    scatter_kernel<<<G, 256, 0, stream>>>(src, dst, ew, blockHist, bucketBase, recs, E, B);
    degdinv_kernel<<<B, 256, 0, stream>>>(bucketBase, recs, dinv, N);

    gemm1_kernel<<<(N + 7) / 8, 256, 0, stream>>>(x, W1, dinv, g1, N);

    const int AGG_BLKS = (E + CHUNK - 1) / CHUNK;   // 12500
    agg1_flat_kernel<<<AGG_BLKS, 256, 0, stream>>>(bucketBase, recs, g1, acc1, E, B);
    combine1_kernel<<<(N + 15) / 16, 256, 0, stream>>>(acc1, g1, dinv, b1, W2, g2, N);
    agg2_flat_kernel<<<AGG_BLKS, 256, 0, stream>>>(bucketBase, recs, g2, acc2, E, B);
    final_kernel<<<(N + 255) / 256, 256, 0, stream>>>(acc2, g2, dinv, b2, Wout, bout, out, N);
}